// Round 13
// baseline (336.811 us; speedup 1.0000x reference)
//
#include <hip/hip_runtime.h>

// 3-layer GraphConv + set pooling + MLP head.
// R13: (1) layer gather reverted to R10 serial staged form (paired gather was
// the R11/R12 regression: <42 -> 49us/layer); (2) CSR build reworked: bucket
// totals via atomics (order within bucket is irrelevant for a sum), killing
// the counts-matrix + 3 scan dispatches. cvt+prepack folded into build pass A.

#define FEAT 64
#define SH 9            // coarse bucket = dst >> 9 (512 nodes/bucket)
#define BSZ 512
#define CH 512          // chunk blocks per build job
#define CAP 12288       // max edges per bucket staged in LDS
#define IDXE 256        // per-wave staged index cap
#define HPAD 8          // LDS row stride = 72 shorts (144B, 16B-aligned)

typedef unsigned short u16;
typedef __attribute__((ext_vector_type(8))) short bf16x8;
typedef __attribute__((ext_vector_type(4))) float f32x4;

__device__ __forceinline__ float bf2f(u16 u) {
  union { unsigned int i; float f; } c; c.i = ((unsigned int)u) << 16; return c.f;
}
__device__ __forceinline__ u16 f2bf(float f) {
  union { float f; unsigned int i; } c; c.f = f;
  unsigned int u = c.i;
  return (u16)((u + 0x7FFFu + ((u >> 16) & 1u)) >> 16);
}

// ---------------- build pass A: bucket totals + cvt + prepack (one dispatch)
__global__ void buildA_kernel(const int* __restrict__ kE, int* __restrict__ btotE, int nE, int NBe,
                              const int* __restrict__ kP, int* __restrict__ btotP, int nP, int NBp,
                              const float* __restrict__ x, u16* __restrict__ xb, int n4, int g_cvt,
                              const float* __restrict__ wr0, const float* __restrict__ wl0,
                              const float* __restrict__ wrh, const float* __restrict__ wlh,
                              u16* __restrict__ wpack) {
  __shared__ int hist[256];
  int tid = threadIdx.x, b = blockIdx.x;
  if (b < 2 * CH) {
    const int* keys; int* btot; int nK, NB, c;
    if (b < CH) { keys = kE; btot = btotE; nK = nE; NB = NBe; c = b; }
    else        { keys = kP; btot = btotP; nK = nP; NB = NBp; c = b - CH; }
    hist[tid] = 0;
    __syncthreads();
    int len = (nK + CH - 1) / CH;
    int cbeg = c * len, cend = min(nK, cbeg + len);
    for (int i = cbeg + tid; i < cend; i += 256) atomicAdd(&hist[keys[i] >> SH], 1);
    __syncthreads();
    if (tid < NB && hist[tid] > 0) atomicAdd(&btot[tid], hist[tid]);
  } else if (b < 2 * CH + g_cvt) {
    int i = (b - 2 * CH) * 256 + tid;
    if (i < n4) {
      float4 v = ((const float4*)x)[i];
      ushort4 o = { f2bf(v.x), f2bf(v.y), f2bf(v.z), f2bf(v.w) };
      ((ushort4*)xb)[i] = o;
    }
  } else {
    int t4 = (b - 2 * CH - g_cvt) * 4 + (tid >> 6);   // tile 0..47
    if (t4 < 48) {
      int l = t4 >> 4, t = t4 & 15;
      int kt = t >> 2, nt = t & 3;
      int lane = tid & 63;
      const float* wr; const float* wl;
      if (l == 0) { wr = wr0; wl = wl0; }
      else        { wr = wrh + (l - 1) * FEAT * FEAT; wl = wlh + (l - 1) * FEAT * FEAT; }
      int n = nt * 16 + (lane & 15);
      int k0 = kt * 32 + (lane >> 4) * 8;
      u16* dst = wpack + (((size_t)l * 16 + t) * 64 + lane) * 8;
#pragma unroll
      for (int j = 0; j < 8; ++j) {
        int k = k0 + j;
        float v = (k < FEAT) ? wr[k * FEAT + n] : wl[(k - FEAT) * FEAT + n];
        dst[j] = f2bf(v);
      }
    }
  }
}

// ---------------- build pass B: scan bucket totals -> bbase + cursors -------
__global__ void buildB_kernel(const int* __restrict__ btotE, int* __restrict__ bbE,
                              int* __restrict__ curE, int NBe, int totE,
                              const int* __restrict__ btotP, int* __restrict__ bbP,
                              int* __restrict__ curP, int NBp, int totP) {
  __shared__ int t[256];
  int tid = threadIdx.x;
  const int* btot; int* bb; int* cur; int NB, tot;
  if (blockIdx.x == 0) { btot = btotE; bb = bbE; cur = curE; NB = NBe; tot = totE; }
  else                 { btot = btotP; bb = bbP; cur = curP; NB = NBp; tot = totP; }
  int v = (tid < NB) ? btot[tid] : 0;
  t[tid] = v;
  __syncthreads();
  for (int off = 1; off < 256; off <<= 1) {
    int u = (tid >= off) ? t[tid - off] : 0;
    __syncthreads();
    t[tid] += u;
    __syncthreads();
  }
  int excl = t[tid] - v;
  if (tid < NB) { bb[tid] = excl; cur[tid] = excl; }
  if (tid == 0) bb[NB] = tot;
}

// ---------------- build pass C: reserve + scatter packed keys ---------------
__global__ void buildC_kernel(const int* __restrict__ s0, const int* __restrict__ k0,
                              int* __restrict__ cur0, int* __restrict__ bin0, int n0, int NB0,
                              const int* __restrict__ s1, const int* __restrict__ k1,
                              int* __restrict__ cur1, int* __restrict__ bin1, int n1, int NB1) {
  __shared__ int hist[256];
  int tid = threadIdx.x, b = blockIdx.x;
  const int* src; const int* keys; int* cur; int* bin; int nE, NB, c;
  if (b < CH) { src = s0; keys = k0; cur = cur0; bin = bin0; nE = n0; NB = NB0; c = b; }
  else        { src = s1; keys = k1; cur = cur1; bin = bin1; nE = n1; NB = NB1; c = b - CH; }
  hist[tid] = 0;
  __syncthreads();
  int len = (nE + CH - 1) / CH;
  int cbeg = c * len, cend = min(nE, cbeg + len);
  for (int i = cbeg + tid; i < cend; i += 256) atomicAdd(&hist[keys[i] >> SH], 1);
  __syncthreads();
  int cnt = (tid < NB) ? hist[tid] : 0;
  __syncthreads();
  if (tid < NB) hist[tid] = (cnt > 0) ? atomicAdd(&cur[tid], cnt) : 0;
  __syncthreads();
  for (int i = cbeg + tid; i < cend; i += 256) {
    int k = keys[i];
    int bu = k >> SH;
    int pos = atomicAdd(&hist[bu], 1);
    bin[pos] = (src[i] << SH) | (k & (BSZ - 1));
  }
}

// ---------------- pass D: per-bucket fine sort + row_start (both jobs) ------
__global__ void __launch_bounds__(256) p2_kernel(const int* __restrict__ bin0,
                                                 const int* __restrict__ bb0,
                                                 int* __restrict__ csr0, int* __restrict__ rs0,
                                                 int nn0, int NB0,
                                                 const int* __restrict__ bin1,
                                                 const int* __restrict__ bb1,
                                                 int* __restrict__ csr1, int* __restrict__ rs1,
                                                 int nn1) {
  __shared__ int s_csr[CAP];
  __shared__ int hist[BSZ];
  __shared__ int excl[BSZ];
  __shared__ int ts[256];
  int tid = threadIdx.x, bb = blockIdx.x;
  const int* bin; const int* bbase; int* csr; int* rs; int n_nodes, b;
  if (bb < NB0) { bin = bin0; bbase = bb0; csr = csr0; rs = rs0; n_nodes = nn0; b = bb; }
  else          { bin = bin1; bbase = bb1; csr = csr1; rs = rs1; n_nodes = nn1; b = bb - NB0; }
  int base = bbase[b];
  int cnt = bbase[b + 1] - base;
  int node_lo = b * BSZ;
  int nnode = min(BSZ, n_nodes - node_lo);

  hist[tid] = 0; hist[tid + 256] = 0;
  __syncthreads();
  for (int i = tid; i < cnt; i += 256) atomicAdd(&hist[bin[base + i] & (BSZ - 1)], 1);
  __syncthreads();

  int a0 = hist[2 * tid], a1 = hist[2 * tid + 1];
  int pair = a0 + a1;
  ts[tid] = pair;
  __syncthreads();
  for (int off = 1; off < 256; off <<= 1) {
    int u = (tid >= off) ? ts[tid - off] : 0;
    __syncthreads();
    ts[tid] += u;
    __syncthreads();
  }
  int pexcl = ts[tid] - pair;
  excl[2 * tid] = pexcl;
  excl[2 * tid + 1] = pexcl + a0;
  __syncthreads();

  for (int t = tid; t < nnode; t += 256) rs[node_lo + t] = base + excl[t];
  if (tid == 0 && node_lo + nnode >= n_nodes) rs[n_nodes] = bbase[(n_nodes + BSZ - 1) / BSZ];
  hist[tid] = excl[tid]; hist[tid + 256] = excl[tid + 256];
  __syncthreads();

  if (cnt <= CAP) {
    for (int i = tid; i < cnt; i += 256) {
      int e = bin[base + i];
      int pos = atomicAdd(&hist[e & (BSZ - 1)], 1);
      s_csr[pos] = e >> SH;
    }
    __syncthreads();
    for (int i = tid; i < cnt; i += 256) csr[base + i] = s_csr[i];
  } else {
    for (int i = tid; i < cnt; i += 256) {
      int e = bin[base + i];
      int pos = atomicAdd(&hist[e & (BSZ - 1)], 1);
      csr[base + pos] = e >> SH;
    }
  }
}

// ---------------- gather helpers (R10 serial form) ----------------
__device__ __forceinline__ float4 reduce_sub(float4 a) {
  a.x += __shfl_xor(a.x, 16, 64); a.y += __shfl_xor(a.y, 16, 64);
  a.z += __shfl_xor(a.z, 16, 64); a.w += __shfl_xor(a.w, 16, 64);
  a.x += __shfl_xor(a.x, 32, 64); a.y += __shfl_xor(a.y, 32, 64);
  a.z += __shfl_xor(a.z, 32, 64); a.w += __shfl_xor(a.w, 32, 64);
  return a;
}

__device__ __forceinline__ float4 wave_gather_acc(const u16* __restrict__ hb,
                                                  const int* idx,
                                                  int d, int sub, int ch) {
  float4 acc = {0.f, 0.f, 0.f, 0.f};
  int i = sub;
  for (; i + 12 < d; i += 16) {
    int s0 = idx[i], s1 = idx[i + 4], s2 = idx[i + 8], s3 = idx[i + 12];
    ushort4 a = ((const ushort4*)(hb + (size_t)s0 * FEAT))[ch];
    ushort4 b = ((const ushort4*)(hb + (size_t)s1 * FEAT))[ch];
    ushort4 c = ((const ushort4*)(hb + (size_t)s2 * FEAT))[ch];
    ushort4 e = ((const ushort4*)(hb + (size_t)s3 * FEAT))[ch];
    acc.x += (bf2f(a.x) + bf2f(b.x)) + (bf2f(c.x) + bf2f(e.x));
    acc.y += (bf2f(a.y) + bf2f(b.y)) + (bf2f(c.y) + bf2f(e.y));
    acc.z += (bf2f(a.z) + bf2f(b.z)) + (bf2f(c.z) + bf2f(e.z));
    acc.w += (bf2f(a.w) + bf2f(b.w)) + (bf2f(c.w) + bf2f(e.w));
  }
  for (; i + 4 < d; i += 8) {
    int s0 = idx[i], s1 = idx[i + 4];
    ushort4 a = ((const ushort4*)(hb + (size_t)s0 * FEAT))[ch];
    ushort4 b = ((const ushort4*)(hb + (size_t)s1 * FEAT))[ch];
    acc.x += bf2f(a.x) + bf2f(b.x);
    acc.y += bf2f(a.y) + bf2f(b.y);
    acc.z += bf2f(a.z) + bf2f(b.z);
    acc.w += bf2f(a.w) + bf2f(b.w);
  }
  if (i < d) {
    int s0 = idx[i];
    ushort4 a = ((const ushort4*)(hb + (size_t)s0 * FEAT))[ch];
    acc.x += bf2f(a.x); acc.y += bf2f(a.y);
    acc.z += bf2f(a.z); acc.w += bf2f(a.w);
  }
  return reduce_sub(acc);
}

// ---------------- fused layer (R10: serial gather + MFMA phase C) -----------
__global__ void __launch_bounds__(512)
layer_fused_kernel(const u16* __restrict__ hb,
                   const int* __restrict__ rs,
                   const int* __restrict__ csr,
                   const u16* __restrict__ wpack,
                   const float* __restrict__ bias,
                   u16* __restrict__ outb, int n) {
  __shared__ u16 s_h[64][FEAT + HPAD];
  __shared__ u16 s_a[64][FEAT + HPAD];
  __shared__ int s_idx[8][IDXE];
  const int tid = threadIdx.x;
  const int wv = __builtin_amdgcn_readfirstlane(tid >> 6);   // 0..7
  const int lane = tid & 63;
  const int sub = lane >> 4;
  const int ch = lane & 15;
  const int base = blockIdx.x * 64;

  // phase B: stage own rows raw (coalesced ushort4)
  for (int it = 0; it < 2; ++it) {
    int idx = tid + it * 512;
    int nl = idx >> 4, c = idx & 15;
    int node = base + nl;
    if (node < n)
      *(ushort4*)&s_h[nl][c * 4] = ((const ushort4*)(hb + (size_t)node * FEAT))[c];
  }

  // phase A: wave wv gathers nodes [base+wv*8, +8), serial with staged idx
  int wbase = base + wv * 8;
  if (wbase < n) {
    int r[9];
#pragma unroll
    for (int j = 0; j < 9; ++j) r[j] = rs[min(wbase + j, n)];
    int rbeg = r[0];
    int run = r[8] - rbeg;
    int* sidx = &s_idx[wv][0];
    bool staged = (run <= IDXE);
    if (staged) {
      for (int i = lane; i < run; i += 64) sidx[i] = csr[rbeg + i];
    }
    int nt = min(8, n - wbase);
    for (int t = 0; t < nt; ++t) {
      int d = r[t + 1] - r[t];
      float4 acc;
      if (staged) acc = wave_gather_acc(hb, sidx + (r[t] - rbeg), d, sub, ch);
      else        acc = wave_gather_acc(hb, csr + r[t], d, sub, ch);
      if (sub == 0) {
        ushort4 o = { f2bf(acc.x), f2bf(acc.y), f2bf(acc.z), f2bf(acc.w) };
        *(ushort4*)&s_a[wv * 8 + t][ch * 4] = o;
      }
    }
  }
  __syncthreads();

  // phase C: MFMA. mt = wv&3, nt pair = (wv>>2)*2, +1.
  const int mt = wv & 3;
  const int ntb = (wv >> 2) * 2;
  const int mrow = mt * 16 + (lane & 15);
  const int koff = (lane >> 4) * 8;
  f32x4 acc0 = {0.f, 0.f, 0.f, 0.f};
  f32x4 acc1 = {0.f, 0.f, 0.f, 0.f};
#pragma unroll
  for (int kt = 0; kt < 4; ++kt) {
    bf16x8 a;
    if (kt < 2) a = *(const bf16x8*)&s_h[mrow][kt * 32 + koff];
    else        a = *(const bf16x8*)&s_a[mrow][(kt - 2) * 32 + koff];
    bf16x8 b0 = *(const bf16x8*)&wpack[(((size_t)kt * 4 + ntb) * 64 + lane) * 8];
    bf16x8 b1 = *(const bf16x8*)&wpack[(((size_t)kt * 4 + ntb + 1) * 64 + lane) * 8];
    acc0 = __builtin_amdgcn_mfma_f32_16x16x32_bf16(a, b0, acc0, 0, 0, 0);
    acc1 = __builtin_amdgcn_mfma_f32_16x16x32_bf16(a, b1, acc1, 0, 0, 0);
  }
  __syncthreads();

  // epilogue: bias + ELU -> bf16 into s_h (D: col=lane&15, row=quad*4+reg)
  const int col = lane & 15;
  const int rbase = (lane >> 4) * 4;
  const float bs0 = bias[ntb * 16 + col];
  const float bs1 = bias[(ntb + 1) * 16 + col];
#pragma unroll
  for (int rg = 0; rg < 4; ++rg) {
    int nl = mt * 16 + rbase + rg;
    float v0 = acc0[rg] + bs0;
    float v1 = acc1[rg] + bs1;
    v0 = v0 > 0.f ? v0 : (__expf(v0) - 1.f);
    v1 = v1 > 0.f ? v1 : (__expf(v1) - 1.f);
    s_h[nl][ntb * 16 + col] = f2bf(v0);
    s_h[nl][(ntb + 1) * 16 + col] = f2bf(v1);
  }
  __syncthreads();

  for (int it = 0; it < 2; ++it) {
    int idx = tid + it * 512;
    int nl = idx >> 4, c = idx & 15;
    int node = base + nl;
    if (node < n)
      ((ushort4*)(outb + (size_t)node * FEAT))[c] = *(const ushort4*)&s_h[nl][c * 4];
  }
}

// ---------------- fused pooling + MLP head (R10 serial gather) --------------
__global__ void __launch_bounds__(512)
pool_mlp_kernel(const u16* __restrict__ hb,
                const int* __restrict__ rs,
                const int* __restrict__ csr,
                const float* __restrict__ fc1_w, const float* __restrict__ fc1_b,
                const float* __restrict__ fc2_w, const float* __restrict__ fc2_b,
                const float* __restrict__ fc3_w, const float* __restrict__ fc3_b,
                float* __restrict__ out, int nsets) {
  __shared__ float s_p[64][FEAT + 4];
  __shared__ int s_idx[8][IDXE];
  const int tid = threadIdx.x;
  const int wv = __builtin_amdgcn_readfirstlane(tid >> 6);
  const int lane = tid & 63;
  const int sub = lane >> 4;
  const int ch = lane & 15;
  const int base = blockIdx.x * 64;

  int wbase = base + wv * 8;
  if (wbase < nsets) {
    int r[9];
#pragma unroll
    for (int j = 0; j < 9; ++j) r[j] = rs[min(wbase + j, nsets)];
    int rbeg = r[0];
    int run = r[8] - rbeg;
    int* sidx = &s_idx[wv][0];
    bool staged = (run <= IDXE);
    if (staged) {
      for (int i = lane; i < run; i += 64) sidx[i] = csr[rbeg + i];
    }
    int nt = min(8, nsets - wbase);
    for (int t = 0; t < nt; ++t) {
      int d = r[t + 1] - r[t];
      float4 acc;
      if (staged) acc = wave_gather_acc(hb, sidx + (r[t] - rbeg), d, sub, ch);
      else        acc = wave_gather_acc(hb, csr + r[t], d, sub, ch);
      if (sub == 0) *(float4*)&s_p[wv * 8 + t][ch * 4] = acc;
    }
  }
  __syncthreads();

  // fc1 (64->64) + ELU, in place; wave covers cols [wv*8, +8)
  {
    const int jb = wv * 8;
    float acc[8];
#pragma unroll
    for (int jj = 0; jj < 8; ++jj) acc[jj] = fc1_b[jb + jj];
    for (int k = 0; k < FEAT; k += 4) {
      const float4 pv = *(const float4*)&s_p[lane][k];
      const float pk[4] = {pv.x, pv.y, pv.z, pv.w};
#pragma unroll
      for (int kk = 0; kk < 4; ++kk) {
        const float* w = fc1_w + (k + kk) * FEAT + jb;
#pragma unroll
        for (int jj = 0; jj < 8; ++jj) acc[jj] += pk[kk] * w[jj];
      }
    }
    __syncthreads();
#pragma unroll
    for (int jj = 0; jj < 8; ++jj) {
      float a = acc[jj];
      s_p[lane][jb + jj] = a > 0.f ? a : (__expf(a) - 1.f);
    }
  }
  __syncthreads();

  // fc2 (64->32) + ELU; wave covers cols [wv*4, +4)
  {
    const int jb = wv * 4;
    float acc[4];
#pragma unroll
    for (int jj = 0; jj < 4; ++jj) acc[jj] = fc2_b[jb + jj];
    for (int k = 0; k < FEAT; k += 4) {
      const float4 tv = *(const float4*)&s_p[lane][k];
      const float tk[4] = {tv.x, tv.y, tv.z, tv.w};
#pragma unroll
      for (int kk = 0; kk < 4; ++kk) {
        const float* w = fc2_w + (k + kk) * 32 + jb;
#pragma unroll
        for (int jj = 0; jj < 4; ++jj) acc[jj] += tk[kk] * w[jj];
      }
    }
    __syncthreads();
#pragma unroll
    for (int jj = 0; jj < 4; ++jj) {
      float a = acc[jj];
      s_p[lane][jb + jj] = a > 0.f ? a : (__expf(a) - 1.f);
    }
  }
  __syncthreads();

  // fc3 (32->2) + log_softmax; wave 0, lane = set
  if (wv == 0) {
    int s = base + lane;
    if (s < nsets) {
      float a0 = fc3_b[0], a1 = fc3_b[1];
      for (int k = 0; k < 32; k += 4) {
        const float4 tv = *(const float4*)&s_p[lane][k];
        const float tk[4] = {tv.x, tv.y, tv.z, tv.w};
#pragma unroll
        for (int kk = 0; kk < 4; ++kk) {
          a0 += tk[kk] * fc3_w[(k + kk) * 2 + 0];
          a1 += tk[kk] * fc3_w[(k + kk) * 2 + 1];
        }
      }
      float m = fmaxf(a0, a1);
      float lse = m + logf(__expf(a0 - m) + __expf(a1 - m));
      float2 r = {a0 - lse, a1 - lse};
      *(float2*)(out + (size_t)s * 2) = r;
    }
  }
}

extern "C" void kernel_launch(void* const* d_in, const int* in_sizes, int n_in,
                              void* d_out, int out_size, void* d_ws, size_t ws_size,
                              hipStream_t stream) {
  const float* x        = (const float*)d_in[0];
  const int* edge_src   = (const int*)d_in[1];
  const int* edge_dst   = (const int*)d_in[2];
  const int* gather_idx = (const int*)d_in[3];
  const int* seg_idx    = (const int*)d_in[4];
  const float* w_root0  = (const float*)d_in[5];
  const float* w_rel0   = (const float*)d_in[6];
  const float* b0       = (const float*)d_in[7];
  const float* w_root_h = (const float*)d_in[8];
  const float* w_rel_h  = (const float*)d_in[9];
  const float* b_h      = (const float*)d_in[10];
  const float* fc1_w    = (const float*)d_in[11];
  const float* fc1_b    = (const float*)d_in[12];
  const float* fc2_w    = (const float*)d_in[13];
  const float* fc2_b    = (const float*)d_in[14];
  const float* fc3_w    = (const float*)d_in[15];
  const float* fc3_b    = (const float*)d_in[16];

  const int N = in_sizes[0] / FEAT;
  const int E = in_sizes[1];
  const int A = in_sizes[3];
  const int S = out_size / 2;

  const int NB_e = (N + BSZ - 1) / BSZ;   // 196
  const int NB_p = (S + BSZ - 1) / BSZ;   // 98

  size_t hrow_bytes = (size_t)N * FEAT * sizeof(u16);
  char* ws = (char*)d_ws;
  size_t off = 0;
  auto alloc = [&](size_t bytes) { void* p = ws + off; off += (bytes + 15) & ~(size_t)15; return p; };
  u16* xb       = (u16*)alloc(hrow_bytes);
  u16* b1b      = (u16*)alloc(hrow_bytes);
  u16* b2b      = (u16*)alloc(hrow_bytes);
  int* csr_e    = (int*)alloc((size_t)E * 4);
  int* bin_e    = (int*)alloc((size_t)E * 4);
  int* rs_e     = (int*)alloc((size_t)(N + 1) * 4);
  int* csr_p    = (int*)alloc((size_t)A * 4);
  int* bin_p    = (int*)alloc((size_t)A * 4);
  int* rs_p     = (int*)alloc((size_t)(S + 1) * 4);
  int* btot_e   = (int*)alloc((size_t)(NB_e) * 4);
  int* btot_p   = (int*)alloc((size_t)(NB_p) * 4);      // contiguous with btot_e
  int* bbase_e  = (int*)alloc((size_t)(NB_e + 1) * 4);
  int* bbase_p  = (int*)alloc((size_t)(NB_p + 1) * 4);
  int* cur_e    = (int*)alloc((size_t)NB_e * 4);
  int* cur_p    = (int*)alloc((size_t)NB_p * 4);
  u16* wpack    = (u16*)alloc((size_t)3 * 16 * 64 * 8 * sizeof(u16));

  dim3 blk(256);
  dim3 blk512(512);

  int n4 = N * FEAT / 4;
  int g_cvt = (n4 + 255) / 256;
  int g_pp = 12;   // 48 prepack tiles / 4 per block

  // ---- build: A (totals + cvt + prepack), B (scan), C (scatter), D (sort) --
  hipMemsetAsync(btot_e, 0, (size_t)(NB_e + NB_p) * 4 + 16, stream);
  buildA_kernel<<<2 * CH + g_cvt + g_pp, blk, 0, stream>>>(
      edge_dst, btot_e, E, NB_e, seg_idx, btot_p, A, NB_p,
      x, xb, n4, g_cvt, w_root0, w_rel0, w_root_h, w_rel_h, wpack);
  buildB_kernel<<<2, blk, 0, stream>>>(btot_e, bbase_e, cur_e, NB_e, E,
                                       btot_p, bbase_p, cur_p, NB_p, A);
  buildC_kernel<<<2 * CH, blk, 0, stream>>>(edge_src, edge_dst, cur_e, bin_e, E, NB_e,
                                            gather_idx, seg_idx, cur_p, bin_p, A, NB_p);
  p2_kernel<<<NB_e + NB_p, blk, 0, stream>>>(bin_e, bbase_e, csr_e, rs_e, N, NB_e,
                                             bin_p, bbase_p, csr_p, rs_p, S);

  int lgrid = (N + 63) / 64;
  int pgrid = (S + 63) / 64;

  // ---- 3 fused GraphConv layers ----
  layer_fused_kernel<<<lgrid, blk512, 0, stream>>>(xb, rs_e, csr_e, wpack,
                                                   b0, b1b, N);
  layer_fused_kernel<<<lgrid, blk512, 0, stream>>>(b1b, rs_e, csr_e, wpack + 16 * 64 * 8,
                                                   b_h, b2b, N);
  layer_fused_kernel<<<lgrid, blk512, 0, stream>>>(b2b, rs_e, csr_e, wpack + 2 * 16 * 64 * 8,
                                                   b_h + FEAT, b1b, N);

  // ---- fused pooling + MLP head + log_softmax ----
  pool_mlp_kernel<<<pgrid, blk512, 0, stream>>>(b1b, rs_p, csr_p,
                                                fc1_w, fc1_b, fc2_w, fc2_b, fc3_w, fc3_b,
                                                (float*)d_out, S);
}

// Round 14
// 300.378 us; speedup vs baseline: 1.1213x; 1.1213x over previous
//
#include <hip/hip_runtime.h>

// 3-layer GraphConv + set pooling + MLP head.
// R14: R10 build pipeline restored (counts-matrix + scans: deterministic
// offsets, one key pass per stage — R13's atomic-reserve build regressed).
// p1b2 upgraded to LDS multi-split: scatter into bucket-grouped LDS, then
// linear coalesced burst copy to global. cvt+prepack folded into p1a2 grid.

#define FEAT 64
#define SH 9            // coarse bucket = dst >> 9 (512 nodes/bucket)
#define BSZ 512
#define CH 512          // chunk blocks per build job
#define CAP 12288       // max edges per bucket staged in LDS (p2)
#define SCHUNK 1024
#define IDXE 256        // per-wave staged index cap
#define HPAD 8          // LDS row stride = 72 shorts (144B, 16B-aligned)
#define LCHUNK 3200     // p1b2 staging cap (>= ceil(E/CH) = 3125)

typedef unsigned short u16;
typedef __attribute__((ext_vector_type(8))) short bf16x8;
typedef __attribute__((ext_vector_type(4))) float f32x4;

__device__ __forceinline__ float bf2f(u16 u) {
  union { unsigned int i; float f; } c; c.i = ((unsigned int)u) << 16; return c.f;
}
__device__ __forceinline__ u16 f2bf(float f) {
  union { float f; unsigned int i; } c; c.f = f;
  unsigned int u = c.i;
  return (u16)((u + 0x7FFFu + ((u >> 16) & 1u)) >> 16);
}

// ------- pass 1a (fused): per-chunk histograms + cvt + weight prepack -------
__global__ void p1a2f_kernel(const int* __restrict__ kE, int* __restrict__ cE, int nE, int NBe,
                             const int* __restrict__ kP, int* __restrict__ cP, int nP, int NBp,
                             const float* __restrict__ x, u16* __restrict__ xb, int n4, int g_cvt,
                             const float* __restrict__ wr0, const float* __restrict__ wl0,
                             const float* __restrict__ wrh, const float* __restrict__ wlh,
                             u16* __restrict__ wpack) {
  __shared__ int hist[256];
  int tid = threadIdx.x, b = blockIdx.x;
  if (b < 2 * CH) {
    const int* keys; int* counts; int nK, NB, c;
    if (b < CH) { keys = kE; counts = cE; nK = nE; NB = NBe; c = b; }
    else        { keys = kP; counts = cP; nK = nP; NB = NBp; c = b - CH; }
    hist[tid] = 0;
    __syncthreads();
    int len = (nK + CH - 1) / CH;
    int cbeg = c * len, cend = min(nK, cbeg + len);
    for (int i = cbeg + tid; i < cend; i += 256) atomicAdd(&hist[keys[i] >> SH], 1);
    __syncthreads();
    if (tid < NB) counts[tid * CH + c] = hist[tid];
  } else if (b < 2 * CH + g_cvt) {
    int i = (b - 2 * CH) * 256 + tid;
    if (i < n4) {
      float4 v = ((const float4*)x)[i];
      ushort4 o = { f2bf(v.x), f2bf(v.y), f2bf(v.z), f2bf(v.w) };
      ((ushort4*)xb)[i] = o;
    }
  } else {
    int t4 = (b - 2 * CH - g_cvt) * 4 + (tid >> 6);   // tile 0..47
    if (t4 < 48) {
      int l = t4 >> 4, t = t4 & 15;
      int kt = t >> 2, nt = t & 3;
      int lane = tid & 63;
      const float* wr; const float* wl;
      if (l == 0) { wr = wr0; wl = wl0; }
      else        { wr = wrh + (l - 1) * FEAT * FEAT; wl = wlh + (l - 1) * FEAT * FEAT; }
      int n = nt * 16 + (lane & 15);
      int k0 = kt * 32 + (lane >> 4) * 8;
      u16* dst = wpack + (((size_t)l * 16 + t) * 64 + lane) * 8;
#pragma unroll
      for (int j = 0; j < 8; ++j) {
        int k = k0 + j;
        float v = (k < FEAT) ? wr[k * FEAT + n] : wl[(k - FEAT) * FEAT + n];
        dst[j] = f2bf(v);
      }
    }
  }
}

// ---------------- multi-block exclusive scan over counts (both jobs) --------
__global__ void scan1_kernel(int* __restrict__ d0, int* __restrict__ bs0, int L0, int nb0,
                             int* __restrict__ d1, int* __restrict__ bs1, int L1) {
  __shared__ int tsum[256];
  int tid = threadIdx.x, b = blockIdx.x;
  int* data; int* bsums; int L, c;
  if (b < nb0) { data = d0; bsums = bs0; L = L0; c = b; }
  else         { data = d1; bsums = bs1; L = L1; c = b - nb0; }
  int base = c * SCHUNK + tid * 4;
  int v[4];
#pragma unroll
  for (int i = 0; i < 4; ++i) v[i] = (base + i < L) ? data[base + i] : 0;
  int local = v[0] + v[1] + v[2] + v[3];
  tsum[tid] = local;
  __syncthreads();
  for (int off = 1; off < 256; off <<= 1) {
    int u = (tid >= off) ? tsum[tid - off] : 0;
    __syncthreads();
    tsum[tid] += u;
    __syncthreads();
  }
  int excl = tsum[tid] - local;
  if (tid == 255) bsums[c] = tsum[255];
  int run = excl;
#pragma unroll
  for (int i = 0; i < 4; ++i) {
    if (base + i < L) data[base + i] = run;
    run += v[i];
  }
}

__global__ void scan2_kernel(int* __restrict__ bs0, int nb0, int* __restrict__ bs1, int nb1) {
  __shared__ int t[256];
  int tid = threadIdx.x;
  int* bsums = (blockIdx.x == 0) ? bs0 : bs1;
  int nb     = (blockIdx.x == 0) ? nb0 : nb1;
  int v = (tid < nb) ? bsums[tid] : 0;
  t[tid] = v;
  __syncthreads();
  for (int off = 1; off < 256; off <<= 1) {
    int u = (tid >= off) ? t[tid - off] : 0;
    __syncthreads();
    t[tid] += u;
    __syncthreads();
  }
  if (tid < nb) bsums[tid] = t[tid] - v;
}

__global__ void scan3_kernel(int* __restrict__ d0, const int* __restrict__ bs0,
                             int* __restrict__ bb0, int L0, int NB0, int tot0, int g0,
                             int* __restrict__ d1, const int* __restrict__ bs1,
                             int* __restrict__ bb1, int L1, int NB1, int tot1) {
  int b = blockIdx.x;
  int* data; const int* bsums; int* bbase; int L, NB, tot, i;
  if (b < g0) { data = d0; bsums = bs0; bbase = bb0; L = L0; NB = NB0; tot = tot0; i = b * 256 + threadIdx.x; }
  else        { data = d1; bsums = bs1; bbase = bb1; L = L1; NB = NB1; tot = tot1; i = (b - g0) * 256 + threadIdx.x; }
  if (i < L) {
    int v = data[i] + bsums[i / SCHUNK];
    data[i] = v;
    if ((i & (CH - 1)) == 0) bbase[i / CH] = v;
  }
  if (i == 0) bbase[NB] = tot;
}

// ------- pass 1b: LDS multi-split scatter with coalesced burst writes -------
__global__ void __launch_bounds__(256)
p1b2_kernel(const int* __restrict__ s0, const int* __restrict__ k0,
            const int* __restrict__ c0, int* __restrict__ bin0, int n0, int NB0,
            const int* __restrict__ s1, const int* __restrict__ k1,
            const int* __restrict__ c1, int* __restrict__ bin1, int n1, int NB1) {
  __shared__ int s_bin[LCHUNK];
  __shared__ unsigned char s_bu[LCHUNK];
  __shared__ int lcur[256];
  __shared__ int gdiff[256];
  __shared__ int ts[256];
  int tid = threadIdx.x, b = blockIdx.x;
  const int* src; const int* keys; const int* counts; int* bin; int nE, NB, c;
  if (b < CH) { src = s0; keys = k0; counts = c0; bin = bin0; nE = n0; NB = NB0; c = b; }
  else        { src = s1; keys = k1; counts = c1; bin = bin1; nE = n1; NB = NB1; c = b - CH; }
  int len = (nE + CH - 1) / CH;
  int cbeg = c * len, cend = min(nE, cbeg + len);
  int L = cend - cbeg;

  // pass 1: local histogram
  lcur[tid] = 0;
  __syncthreads();
  for (int i = cbeg + tid; i < cend; i += 256) atomicAdd(&lcur[keys[i] >> SH], 1);
  __syncthreads();

  // local exclusive scan; gdiff = global chunk offset - local base
  int v = lcur[tid];
  ts[tid] = v;
  __syncthreads();
  for (int off = 1; off < 256; off <<= 1) {
    int u = (tid >= off) ? ts[tid - off] : 0;
    __syncthreads();
    ts[tid] += u;
    __syncthreads();
  }
  int excl = ts[tid] - v;
  __syncthreads();
  lcur[tid] = excl;
  gdiff[tid] = ((tid < NB) ? counts[tid * CH + c] : 0) - excl;
  __syncthreads();

  if (L <= LCHUNK) {
    // pass 2: scatter into bucket-grouped LDS
    for (int i = cbeg + tid; i < cend; i += 256) {
      int k = keys[i];
      int bu = k >> SH;
      int pos = atomicAdd(&lcur[bu], 1);
      s_bin[pos] = (src[i] << SH) | (k & (BSZ - 1));
      s_bu[pos] = (unsigned char)bu;
    }
    __syncthreads();
    // pass 3: linear copy -> coalesced bursts per bucket segment
    for (int i = tid; i < L; i += 256) {
      int bu = s_bu[i];
      bin[gdiff[bu] + i] = s_bin[i];
    }
  } else {
    // fallback: direct scatter
    for (int i = cbeg + tid; i < cend; i += 256) {
      int k = keys[i];
      int bu = k >> SH;
      int pos = atomicAdd(&lcur[bu], 1);
      bin[gdiff[bu] + pos] = (src[i] << SH) | (k & (BSZ - 1));
    }
  }
}

// ---------------- pass 2: per-bucket fine sort + row_start (both jobs) ------
__global__ void __launch_bounds__(256) p2_kernel(const int* __restrict__ bin0,
                                                 const int* __restrict__ bb0,
                                                 int* __restrict__ csr0, int* __restrict__ rs0,
                                                 int nn0, int NB0,
                                                 const int* __restrict__ bin1,
                                                 const int* __restrict__ bb1,
                                                 int* __restrict__ csr1, int* __restrict__ rs1,
                                                 int nn1) {
  __shared__ int s_csr[CAP];
  __shared__ int hist[BSZ];
  __shared__ int excl[BSZ];
  __shared__ int ts[256];
  int tid = threadIdx.x, bb = blockIdx.x;
  const int* bin; const int* bbase; int* csr; int* rs; int n_nodes, b;
  if (bb < NB0) { bin = bin0; bbase = bb0; csr = csr0; rs = rs0; n_nodes = nn0; b = bb; }
  else          { bin = bin1; bbase = bb1; csr = csr1; rs = rs1; n_nodes = nn1; b = bb - NB0; }
  int base = bbase[b];
  int cnt = bbase[b + 1] - base;
  int node_lo = b * BSZ;
  int nnode = min(BSZ, n_nodes - node_lo);

  hist[tid] = 0; hist[tid + 256] = 0;
  __syncthreads();
  for (int i = tid; i < cnt; i += 256) atomicAdd(&hist[bin[base + i] & (BSZ - 1)], 1);
  __syncthreads();

  int a0 = hist[2 * tid], a1 = hist[2 * tid + 1];
  int pair = a0 + a1;
  ts[tid] = pair;
  __syncthreads();
  for (int off = 1; off < 256; off <<= 1) {
    int u = (tid >= off) ? ts[tid - off] : 0;
    __syncthreads();
    ts[tid] += u;
    __syncthreads();
  }
  int pexcl = ts[tid] - pair;
  excl[2 * tid] = pexcl;
  excl[2 * tid + 1] = pexcl + a0;
  __syncthreads();

  for (int t = tid; t < nnode; t += 256) rs[node_lo + t] = base + excl[t];
  if (tid == 0 && node_lo + nnode >= n_nodes) rs[n_nodes] = bbase[(n_nodes + BSZ - 1) / BSZ];
  hist[tid] = excl[tid]; hist[tid + 256] = excl[tid + 256];
  __syncthreads();

  if (cnt <= CAP) {
    for (int i = tid; i < cnt; i += 256) {
      int e = bin[base + i];
      int pos = atomicAdd(&hist[e & (BSZ - 1)], 1);
      s_csr[pos] = e >> SH;
    }
    __syncthreads();
    for (int i = tid; i < cnt; i += 256) csr[base + i] = s_csr[i];
  } else {
    for (int i = tid; i < cnt; i += 256) {
      int e = bin[base + i];
      int pos = atomicAdd(&hist[e & (BSZ - 1)], 1);
      csr[base + pos] = e >> SH;
    }
  }
}

// ---------------- gather helpers (R10 serial form) ----------------
__device__ __forceinline__ float4 reduce_sub(float4 a) {
  a.x += __shfl_xor(a.x, 16, 64); a.y += __shfl_xor(a.y, 16, 64);
  a.z += __shfl_xor(a.z, 16, 64); a.w += __shfl_xor(a.w, 16, 64);
  a.x += __shfl_xor(a.x, 32, 64); a.y += __shfl_xor(a.y, 32, 64);
  a.z += __shfl_xor(a.z, 32, 64); a.w += __shfl_xor(a.w, 32, 64);
  return a;
}

__device__ __forceinline__ float4 wave_gather_acc(const u16* __restrict__ hb,
                                                  const int* idx,
                                                  int d, int sub, int ch) {
  float4 acc = {0.f, 0.f, 0.f, 0.f};
  int i = sub;
  for (; i + 12 < d; i += 16) {
    int s0 = idx[i], s1 = idx[i + 4], s2 = idx[i + 8], s3 = idx[i + 12];
    ushort4 a = ((const ushort4*)(hb + (size_t)s0 * FEAT))[ch];
    ushort4 b = ((const ushort4*)(hb + (size_t)s1 * FEAT))[ch];
    ushort4 c = ((const ushort4*)(hb + (size_t)s2 * FEAT))[ch];
    ushort4 e = ((const ushort4*)(hb + (size_t)s3 * FEAT))[ch];
    acc.x += (bf2f(a.x) + bf2f(b.x)) + (bf2f(c.x) + bf2f(e.x));
    acc.y += (bf2f(a.y) + bf2f(b.y)) + (bf2f(c.y) + bf2f(e.y));
    acc.z += (bf2f(a.z) + bf2f(b.z)) + (bf2f(c.z) + bf2f(e.z));
    acc.w += (bf2f(a.w) + bf2f(b.w)) + (bf2f(c.w) + bf2f(e.w));
  }
  for (; i + 4 < d; i += 8) {
    int s0 = idx[i], s1 = idx[i + 4];
    ushort4 a = ((const ushort4*)(hb + (size_t)s0 * FEAT))[ch];
    ushort4 b = ((const ushort4*)(hb + (size_t)s1 * FEAT))[ch];
    acc.x += bf2f(a.x) + bf2f(b.x);
    acc.y += bf2f(a.y) + bf2f(b.y);
    acc.z += bf2f(a.z) + bf2f(b.z);
    acc.w += bf2f(a.w) + bf2f(b.w);
  }
  if (i < d) {
    int s0 = idx[i];
    ushort4 a = ((const ushort4*)(hb + (size_t)s0 * FEAT))[ch];
    acc.x += bf2f(a.x); acc.y += bf2f(a.y);
    acc.z += bf2f(a.z); acc.w += bf2f(a.w);
  }
  return reduce_sub(acc);
}

// ---------------- fused layer (serial staged gather + MFMA phase C) ---------
__global__ void __launch_bounds__(512)
layer_fused_kernel(const u16* __restrict__ hb,
                   const int* __restrict__ rs,
                   const int* __restrict__ csr,
                   const u16* __restrict__ wpack,
                   const float* __restrict__ bias,
                   u16* __restrict__ outb, int n) {
  __shared__ u16 s_h[64][FEAT + HPAD];
  __shared__ u16 s_a[64][FEAT + HPAD];
  __shared__ int s_idx[8][IDXE];
  const int tid = threadIdx.x;
  const int wv = __builtin_amdgcn_readfirstlane(tid >> 6);   // 0..7
  const int lane = tid & 63;
  const int sub = lane >> 4;
  const int ch = lane & 15;
  const int base = blockIdx.x * 64;

  // phase B: stage own rows raw (coalesced ushort4)
  for (int it = 0; it < 2; ++it) {
    int idx = tid + it * 512;
    int nl = idx >> 4, c = idx & 15;
    int node = base + nl;
    if (node < n)
      *(ushort4*)&s_h[nl][c * 4] = ((const ushort4*)(hb + (size_t)node * FEAT))[c];
  }

  // phase A: wave wv gathers nodes [base+wv*8, +8), serial with staged idx
  int wbase = base + wv * 8;
  if (wbase < n) {
    int r[9];
#pragma unroll
    for (int j = 0; j < 9; ++j) r[j] = rs[min(wbase + j, n)];
    int rbeg = r[0];
    int run = r[8] - rbeg;
    int* sidx = &s_idx[wv][0];
    bool staged = (run <= IDXE);
    if (staged) {
      for (int i = lane; i < run; i += 64) sidx[i] = csr[rbeg + i];
    }
    int nt = min(8, n - wbase);
    for (int t = 0; t < nt; ++t) {
      int d = r[t + 1] - r[t];
      float4 acc;
      if (staged) acc = wave_gather_acc(hb, sidx + (r[t] - rbeg), d, sub, ch);
      else        acc = wave_gather_acc(hb, csr + r[t], d, sub, ch);
      if (sub == 0) {
        ushort4 o = { f2bf(acc.x), f2bf(acc.y), f2bf(acc.z), f2bf(acc.w) };
        *(ushort4*)&s_a[wv * 8 + t][ch * 4] = o;
      }
    }
  }
  __syncthreads();

  // phase C: MFMA. mt = wv&3, nt pair = (wv>>2)*2, +1.
  const int mt = wv & 3;
  const int ntb = (wv >> 2) * 2;
  const int mrow = mt * 16 + (lane & 15);
  const int koff = (lane >> 4) * 8;
  f32x4 acc0 = {0.f, 0.f, 0.f, 0.f};
  f32x4 acc1 = {0.f, 0.f, 0.f, 0.f};
#pragma unroll
  for (int kt = 0; kt < 4; ++kt) {
    bf16x8 a;
    if (kt < 2) a = *(const bf16x8*)&s_h[mrow][kt * 32 + koff];
    else        a = *(const bf16x8*)&s_a[mrow][(kt - 2) * 32 + koff];
    bf16x8 b0 = *(const bf16x8*)&wpack[(((size_t)kt * 4 + ntb) * 64 + lane) * 8];
    bf16x8 b1 = *(const bf16x8*)&wpack[(((size_t)kt * 4 + ntb + 1) * 64 + lane) * 8];
    acc0 = __builtin_amdgcn_mfma_f32_16x16x32_bf16(a, b0, acc0, 0, 0, 0);
    acc1 = __builtin_amdgcn_mfma_f32_16x16x32_bf16(a, b1, acc1, 0, 0, 0);
  }
  __syncthreads();

  // epilogue: bias + ELU -> bf16 into s_h (D: col=lane&15, row=quad*4+reg)
  const int col = lane & 15;
  const int rbase = (lane >> 4) * 4;
  const float bs0 = bias[ntb * 16 + col];
  const float bs1 = bias[(ntb + 1) * 16 + col];
#pragma unroll
  for (int rg = 0; rg < 4; ++rg) {
    int nl = mt * 16 + rbase + rg;
    float v0 = acc0[rg] + bs0;
    float v1 = acc1[rg] + bs1;
    v0 = v0 > 0.f ? v0 : (__expf(v0) - 1.f);
    v1 = v1 > 0.f ? v1 : (__expf(v1) - 1.f);
    s_h[nl][ntb * 16 + col] = f2bf(v0);
    s_h[nl][(ntb + 1) * 16 + col] = f2bf(v1);
  }
  __syncthreads();

  for (int it = 0; it < 2; ++it) {
    int idx = tid + it * 512;
    int nl = idx >> 4, c = idx & 15;
    int node = base + nl;
    if (node < n)
      ((ushort4*)(outb + (size_t)node * FEAT))[c] = *(const ushort4*)&s_h[nl][c * 4];
  }
}

// ---------------- fused pooling + MLP head (serial staged gather) -----------
__global__ void __launch_bounds__(512)
pool_mlp_kernel(const u16* __restrict__ hb,
                const int* __restrict__ rs,
                const int* __restrict__ csr,
                const float* __restrict__ fc1_w, const float* __restrict__ fc1_b,
                const float* __restrict__ fc2_w, const float* __restrict__ fc2_b,
                const float* __restrict__ fc3_w, const float* __restrict__ fc3_b,
                float* __restrict__ out, int nsets) {
  __shared__ float s_p[64][FEAT + 4];
  __shared__ int s_idx[8][IDXE];
  const int tid = threadIdx.x;
  const int wv = __builtin_amdgcn_readfirstlane(tid >> 6);
  const int lane = tid & 63;
  const int sub = lane >> 4;
  const int ch = lane & 15;
  const int base = blockIdx.x * 64;

  int wbase = base + wv * 8;
  if (wbase < nsets) {
    int r[9];
#pragma unroll
    for (int j = 0; j < 9; ++j) r[j] = rs[min(wbase + j, nsets)];
    int rbeg = r[0];
    int run = r[8] - rbeg;
    int* sidx = &s_idx[wv][0];
    bool staged = (run <= IDXE);
    if (staged) {
      for (int i = lane; i < run; i += 64) sidx[i] = csr[rbeg + i];
    }
    int nt = min(8, nsets - wbase);
    for (int t = 0; t < nt; ++t) {
      int d = r[t + 1] - r[t];
      float4 acc;
      if (staged) acc = wave_gather_acc(hb, sidx + (r[t] - rbeg), d, sub, ch);
      else        acc = wave_gather_acc(hb, csr + r[t], d, sub, ch);
      if (sub == 0) *(float4*)&s_p[wv * 8 + t][ch * 4] = acc;
    }
  }
  __syncthreads();

  // fc1 (64->64) + ELU, in place; wave covers cols [wv*8, +8)
  {
    const int jb = wv * 8;
    float acc[8];
#pragma unroll
    for (int jj = 0; jj < 8; ++jj) acc[jj] = fc1_b[jb + jj];
    for (int k = 0; k < FEAT; k += 4) {
      const float4 pv = *(const float4*)&s_p[lane][k];
      const float pk[4] = {pv.x, pv.y, pv.z, pv.w};
#pragma unroll
      for (int kk = 0; kk < 4; ++kk) {
        const float* w = fc1_w + (k + kk) * FEAT + jb;
#pragma unroll
        for (int jj = 0; jj < 8; ++jj) acc[jj] += pk[kk] * w[jj];
      }
    }
    __syncthreads();
#pragma unroll
    for (int jj = 0; jj < 8; ++jj) {
      float a = acc[jj];
      s_p[lane][jb + jj] = a > 0.f ? a : (__expf(a) - 1.f);
    }
  }
  __syncthreads();

  // fc2 (64->32) + ELU; wave covers cols [wv*4, +4)
  {
    const int jb = wv * 4;
    float acc[4];
#pragma unroll
    for (int jj = 0; jj < 4; ++jj) acc[jj] = fc2_b[jb + jj];
    for (int k = 0; k < FEAT; k += 4) {
      const float4 tv = *(const float4*)&s_p[lane][k];
      const float tk[4] = {tv.x, tv.y, tv.z, tv.w};
#pragma unroll
      for (int kk = 0; kk < 4; ++kk) {
        const float* w = fc2_w + (k + kk) * 32 + jb;
#pragma unroll
        for (int jj = 0; jj < 4; ++jj) acc[jj] += tk[kk] * w[jj];
      }
    }
    __syncthreads();
#pragma unroll
    for (int jj = 0; jj < 4; ++jj) {
      float a = acc[jj];
      s_p[lane][jb + jj] = a > 0.f ? a : (__expf(a) - 1.f);
    }
  }
  __syncthreads();

  // fc3 (32->2) + log_softmax; wave 0, lane = set
  if (wv == 0) {
    int s = base + lane;
    if (s < nsets) {
      float a0 = fc3_b[0], a1 = fc3_b[1];
      for (int k = 0; k < 32; k += 4) {
        const float4 tv = *(const float4*)&s_p[lane][k];
        const float tk[4] = {tv.x, tv.y, tv.z, tv.w};
#pragma unroll
        for (int kk = 0; kk < 4; ++kk) {
          a0 += tk[kk] * fc3_w[(k + kk) * 2 + 0];
          a1 += tk[kk] * fc3_w[(k + kk) * 2 + 1];
        }
      }
      float m = fmaxf(a0, a1);
      float lse = m + logf(__expf(a0 - m) + __expf(a1 - m));
      float2 r = {a0 - lse, a1 - lse};
      *(float2*)(out + (size_t)s * 2) = r;
    }
  }
}

extern "C" void kernel_launch(void* const* d_in, const int* in_sizes, int n_in,
                              void* d_out, int out_size, void* d_ws, size_t ws_size,
                              hipStream_t stream) {
  const float* x        = (const float*)d_in[0];
  const int* edge_src   = (const int*)d_in[1];
  const int* edge_dst   = (const int*)d_in[2];
  const int* gather_idx = (const int*)d_in[3];
  const int* seg_idx    = (const int*)d_in[4];
  const float* w_root0  = (const float*)d_in[5];
  const float* w_rel0   = (const float*)d_in[6];
  const float* b0       = (const float*)d_in[7];
  const float* w_root_h = (const float*)d_in[8];
  const float* w_rel_h  = (const float*)d_in[9];
  const float* b_h      = (const float*)d_in[10];
  const float* fc1_w    = (const float*)d_in[11];
  const float* fc1_b    = (const float*)d_in[12];
  const float* fc2_w    = (const float*)d_in[13];
  const float* fc2_b    = (const float*)d_in[14];
  const float* fc3_w    = (const float*)d_in[15];
  const float* fc3_b    = (const float*)d_in[16];

  const int N = in_sizes[0] / FEAT;
  const int E = in_sizes[1];
  const int A = in_sizes[3];
  const int S = out_size / 2;

  const int NB_e = (N + BSZ - 1) / BSZ;
  const int NB_p = (S + BSZ - 1) / BSZ;
  const int L_e = NB_e * CH, L_p = NB_p * CH;
  const int nb_e = (L_e + SCHUNK - 1) / SCHUNK;
  const int nb_p = (L_p + SCHUNK - 1) / SCHUNK;
  const int g_e = (L_e + 255) / 256, g_p = (L_p + 255) / 256;

  size_t hrow_bytes = (size_t)N * FEAT * sizeof(u16);
  char* ws = (char*)d_ws;
  size_t off = 0;
  auto alloc = [&](size_t bytes) { void* p = ws + off; off += (bytes + 15) & ~(size_t)15; return p; };
  u16* xb       = (u16*)alloc(hrow_bytes);
  u16* b1b      = (u16*)alloc(hrow_bytes);
  u16* b2b      = (u16*)alloc(hrow_bytes);
  int* csr_e    = (int*)alloc((size_t)E * 4);
  int* bin_e    = (int*)alloc((size_t)E * 4);
  int* rs_e     = (int*)alloc((size_t)(N + 1) * 4);
  int* counts_e = (int*)alloc((size_t)L_e * 4);
  int* bbase_e  = (int*)alloc((size_t)(NB_e + 1) * 4);
  int* csr_p    = (int*)alloc((size_t)A * 4);
  int* bin_p    = (int*)alloc((size_t)A * 4);
  int* rs_p     = (int*)alloc((size_t)(S + 1) * 4);
  int* counts_p = (int*)alloc((size_t)L_p * 4);
  int* bbase_p  = (int*)alloc((size_t)(NB_p + 1) * 4);
  int* bsums_e  = (int*)alloc(256 * 4);
  int* bsums_p  = (int*)alloc(256 * 4);
  u16* wpack    = (u16*)alloc((size_t)3 * 16 * 64 * 8 * sizeof(u16));

  dim3 blk(256);
  dim3 blk512(512);

  int n4 = N * FEAT / 4;
  int g_cvt = (n4 + 255) / 256;
  int g_pp = 12;

  // ---- build both CSRs (+ cvt + prepack folded into pass 1a) ----
  p1a2f_kernel<<<2 * CH + g_cvt + g_pp, blk, 0, stream>>>(
      edge_dst, counts_e, E, NB_e, seg_idx, counts_p, A, NB_p,
      x, xb, n4, g_cvt, w_root0, w_rel0, w_root_h, w_rel_h, wpack);
  scan1_kernel<<<nb_e + nb_p, blk, 0, stream>>>(counts_e, bsums_e, L_e, nb_e,
                                                counts_p, bsums_p, L_p);
  scan2_kernel<<<2, blk, 0, stream>>>(bsums_e, nb_e, bsums_p, nb_p);
  scan3_kernel<<<g_e + g_p, blk, 0, stream>>>(counts_e, bsums_e, bbase_e, L_e, NB_e, E, g_e,
                                              counts_p, bsums_p, bbase_p, L_p, NB_p, A);
  p1b2_kernel<<<2 * CH, blk, 0, stream>>>(edge_src, edge_dst, counts_e, bin_e, E, NB_e,
                                          gather_idx, seg_idx, counts_p, bin_p, A, NB_p);
  p2_kernel<<<NB_e + NB_p, blk, 0, stream>>>(bin_e, bbase_e, csr_e, rs_e, N, NB_e,
                                             bin_p, bbase_p, csr_p, rs_p, S);

  int lgrid = (N + 63) / 64;
  int pgrid = (S + 63) / 64;

  // ---- 3 fused GraphConv layers ----
  layer_fused_kernel<<<lgrid, blk512, 0, stream>>>(xb, rs_e, csr_e, wpack,
                                                   b0, b1b, N);
  layer_fused_kernel<<<lgrid, blk512, 0, stream>>>(b1b, rs_e, csr_e, wpack + 16 * 64 * 8,
                                                   b_h, b2b, N);
  layer_fused_kernel<<<lgrid, blk512, 0, stream>>>(b2b, rs_e, csr_e, wpack + 2 * 16 * 64 * 8,
                                                   b_h + FEAT, b1b, N);

  // ---- fused pooling + MLP head + log_softmax ----
  pool_mlp_kernel<<<pgrid, blk512, 0, stream>>>(b1b, rs_p, csr_p,
                                                fc1_w, fc1_b, fc2_w, fc2_b, fc3_w, fc3_b,
                                                (float*)d_out, S);
}